// Round 6
// baseline (493.313 us; speedup 1.0000x reference)
//
#include <hip/hip_runtime.h>

typedef __attribute__((ext_vector_type(8))) short s16x8;
typedef __attribute__((ext_vector_type(4))) float f32x4;

#define MFMA16 __builtin_amdgcn_mfma_f32_16x16x32_bf16

__device__ __forceinline__ short f2bf(float x) {
  union { float f; unsigned u; } c; c.f = x;
  unsigned r = (c.u + 0x7fffu + ((c.u >> 16) & 1u)) >> 16;
  return (short)r;
}

__device__ __forceinline__ void gld16(const void* g, void* l) {
  __builtin_amdgcn_global_load_lds(
      (const __attribute__((address_space(1))) unsigned*)g,
      (__attribute__((address_space(3))) unsigned*)l, 16, 0, 0);
}

// BK=32 LDS tiles: involution slot ^= (row>>1)&3 on BOTH gld_lds source and
// ds_read (R3-verified, 0 conflicts):
//   stage: srow = lane>>2, selem = ((lane&3)^((lane>>3)&3))*8
//   read : koff = ((lane>>4)^((lane>>1)&3))*8
// A2F fragment-major layout (NEW): per bu, 16B chunk (kt6, ks, w) at
//   ((kt6*4+ks)*256 + w)*8 + f&7  where kt6 = kf>>5, ks = (kf>>3)&3.
// Phase-1 a-frag loads from A2F are 256B-contiguous per quarter-wave.

// ---------------------------------------------------------------------------
// Prep
// ---------------------------------------------------------------------------
__global__ __launch_bounds__(256) void k_cvt_l1(const float* __restrict__ L1,
                                                short* __restrict__ L1b) {
  int i = blockIdx.x * 256 + threadIdx.x;
  L1b[i] = f2bf(L1[i]);
}

__global__ __launch_bounds__(256) void k_build_l2cat(const float* __restrict__ L2,
                                                     short* __restrict__ L2cat) {
  __shared__ float t[32][33];
  const int l = blockIdx.z, w0 = blockIdx.x * 32, z0 = blockIdx.y * 32;
  const int tx = threadIdx.x, ty = threadIdx.y;
  const float* src = L2 + (size_t)l * 65536;
  for (int i = ty; i < 32; i += 8) t[i][tx] = src[(size_t)(w0 + i) * 256 + z0 + tx];
  __syncthreads();
  for (int i = ty; i < 32; i += 8)
    L2cat[(size_t)(z0 + i) * 768 + l * 256 + w0 + tx] = f2bf(t[tx][i]);
}

__global__ __launch_bounds__(256) void k_build_wt(const float* __restrict__ W,
                                                  short* __restrict__ WT) {
  for (int idx = threadIdx.x + blockIdx.x * 256; idx < 192 * 192; idx += 256 * gridDim.x) {
    int lo = idx / 192, kf = idx % 192;
    int l = lo >> 6, o = lo & 63, k = kf / 64, f = kf & 63;
    WT[idx] = f2bf(W[(((size_t)(k * 3 + l) * 64 + f) << 6) + o]);
  }
}

__global__ __launch_bounds__(256) void k_cvt_ht(const float* __restrict__ H,
                                                short* __restrict__ HbT, int b0) {
  __shared__ float t[32][33];
  const int bc = blockIdx.z;
  const int wf0 = blockIdx.x * 32, v0 = blockIdx.y * 32;
  const int tx = threadIdx.x, ty = threadIdx.y;
  const float* src = H + ((size_t)(b0 + bc) * 256 + v0) * 16384;
  for (int i = ty; i < 32; i += 8) t[i][tx] = src[(size_t)i * 16384 + wf0 + tx];
  __syncthreads();
  short* dst = HbT + ((size_t)bc * 16384 + wf0) * 256;
  for (int i = ty; i < 32; i += 8) dst[(size_t)i * 256 + v0 + tx] = f2bf(t[tx][i]);
}

// ---------------------------------------------------------------------------
// S1: A2F fragments = sum_v L1b[kk][u][v]*HbT[bc][w*64+f][v]
// 128x128 tile, BK=32, double-buffered; C-write in A2F fragment-major layout.
// ---------------------------------------------------------------------------
__global__ __launch_bounds__(256, 4) void k_s1(const short* __restrict__ L1b,
                                               const short* __restrict__ HbT,
                                               short* __restrict__ A2F) {
  __shared__ __align__(16) short At[2][128 * 32];
  __shared__ __align__(16) short Bt[2][128 * 32];
  const int t = threadIdx.x, lane = t & 63, wid = t >> 6;
  const int n0 = blockIdx.x * 128;
  const int kk = blockIdx.y >> 1;
  const int u0 = (blockIdx.y & 1) * 128;
  const int bc = blockIdx.z;
  const short* Ag = L1b + (size_t)kk * 65536;
  const short* Bg = HbT + (size_t)bc * 16384 * 256;
  const int wm = wid >> 1, wn = wid & 1;
  const int srow = lane >> 2;
  const int selem = ((lane & 3) ^ ((lane >> 3) & 3)) * 8;
  const int koff = ((lane >> 4) ^ ((lane >> 1) & 3)) * 8;
  const int ar = lane & 15;
#pragma unroll
  for (int j = 0; j < 2; ++j) {
    const int rb = wid * 32 + j * 16;
    gld16(Ag + (size_t)(u0 + rb + srow) * 256 + selem, At[0] + rb * 32);
    gld16(Bg + (size_t)(n0 + rb + srow) * 256 + selem, Bt[0] + rb * 32);
  }
  __syncthreads();
  f32x4 acc[4][4] = {};
#pragma unroll
  for (int kt8 = 0; kt8 < 8; ++kt8) {
    const int cur = kt8 & 1;
    s16x8 a[4], b[4];
#pragma unroll
    for (int i = 0; i < 4; ++i)
      a[i] = *(const s16x8*)&At[cur][(wm * 64 + i * 16 + ar) * 32 + koff];
#pragma unroll
    for (int j = 0; j < 4; ++j)
      b[j] = *(const s16x8*)&Bt[cur][(wn * 64 + j * 16 + ar) * 32 + koff];
    if (kt8 < 7) {
#pragma unroll
      for (int j = 0; j < 2; ++j) {
        const int rb = wid * 32 + j * 16;
        gld16(Ag + (size_t)(u0 + rb + srow) * 256 + (kt8 + 1) * 32 + selem, At[cur ^ 1] + rb * 32);
        gld16(Bg + (size_t)(n0 + rb + srow) * 256 + (kt8 + 1) * 32 + selem, Bt[cur ^ 1] + rb * 32);
      }
    }
#pragma unroll
    for (int i = 0; i < 4; ++i)
#pragma unroll
      for (int j = 0; j < 4; ++j) acc[i][j] = MFMA16(a[i], b[j], acc[i][j], 0, 0, 0);
    __syncthreads();
  }
  const int cr = lane >> 4, cc = lane & 15;
#pragma unroll
  for (int i = 0; i < 4; ++i)
#pragma unroll
    for (int j = 0; j < 4; ++j) {
      const int ncol = n0 + wn * 64 + j * 16 + cc;
      const int w = ncol >> 6, f = ncol & 63;
      const int kt6 = kk * 2 + (f >> 5), ksw = (f >> 3) & 3, f7 = f & 7;
      const int off = ((kt6 * 4 + ksw) * 256 + w) * 8 + f7;
#pragma unroll
      for (int r = 0; r < 4; ++r) {
        const int u = u0 + wm * 64 + i * 16 + cr * 4 + r;
        A2F[(size_t)(bc * 256 + u) * 49152 + off] = f2bf(acc[i][j][r]);
      }
    }
}

// ---------------------------------------------------------------------------
// S2+S3 fused, o-split (2 blocks/bu). LDS = 48 KB (Ws 36K overlaid by P 48K).
// Both phases: global->register a-frags, rotating depth-3 prefetch (static
// indices), b-frags from LDS. Only 2 barriers in the whole kernel.
// ---------------------------------------------------------------------------
__global__ __launch_bounds__(512, 4) void k_s23(const short* __restrict__ A2F,
                                                const short* __restrict__ WTg,
                                                const short* __restrict__ L2cat,
                                                const float* __restrict__ bias,
                                                float* __restrict__ out, int b0) {
  __shared__ __align__(16) short P[32 * 768];  // 48 KB; Ws overlays [0,36K)
  short* Ws = P;
  const int t = threadIdx.x, lane = t & 63, wid = t >> 6;
  const int bx = blockIdx.x;
  const int bul = (bx & 7) | ((bx >> 4) << 3);  // o-pair 8 apart -> same XCD
  const int o0 = ((bx >> 3) & 1) * 32;
  const int ar = lane & 15, cc = ar, cr = lane >> 4, sl = lane & 7, ks = lane >> 4;
  const int srow = lane >> 2;
  const int selem = ((lane & 3) ^ ((lane >> 3) & 3)) * 8;
  const int koff = ((lane >> 4) ^ ((lane >> 1) & 3)) * 8;
  const short* A2g = A2F + (size_t)bul * 49152;

#define ALOAD(kt6, i) \
  (*(const s16x8*)&A2g[(((kt6) * 4 + ks) * 256 + wid * 32 + (i) * 16 + ar) * 8])
#define ZLOAD(t2, i) \
  (*(const s16x8*)&L2cat[(size_t)(wid * 32 + (i) * 16 + ar) * 768 + (t2) * 32 + ks * 8])

  // prologue: phase-1 a prefetch (regs) + Ws stage (LDS, gld_lds)
  s16x8 apf0[2], apf1[2], apf2[2];
  apf0[0] = ALOAD(0, 0); apf0[1] = ALOAD(0, 1);
  apf1[0] = ALOAD(1, 0); apf1[1] = ALOAD(1, 1);
  apf2[0] = ALOAD(2, 0); apf2[1] = ALOAD(2, 1);
  for (int s = wid; s < 36; s += 8) {
    const int t6 = s / 6, rb = (s % 6) * 16;
    const int gr = (rb >> 5) * 64 + o0 + (rb & 31);
    gld16(WTg + (size_t)(gr + srow) * 192 + t6 * 32 + selem, Ws + (t6 * 96 + rb) * 32);
  }
  __syncthreads();

  // ---- Phase 1: (96 lo') x (own 32 w), K=192 ----
  f32x4 acc[3][2][2] = {};
#pragma unroll
  for (int kt6 = 0; kt6 < 6; ++kt6) {
    s16x8 a0, a1;
    if (kt6 % 3 == 0)      { a0 = apf0[0]; a1 = apf0[1]; }
    else if (kt6 % 3 == 1) { a0 = apf1[0]; a1 = apf1[1]; }
    else                   { a0 = apf2[0]; a1 = apf2[1]; }
    if (kt6 < 3) {
      if (kt6 % 3 == 0)      { apf0[0] = ALOAD(kt6 + 3, 0); apf0[1] = ALOAD(kt6 + 3, 1); }
      else if (kt6 % 3 == 1) { apf1[0] = ALOAD(kt6 + 3, 0); apf1[1] = ALOAD(kt6 + 3, 1); }
      else                   { apf2[0] = ALOAD(kt6 + 3, 0); apf2[1] = ALOAD(kt6 + 3, 1); }
    }
#pragma unroll
    for (int l = 0; l < 3; ++l)
#pragma unroll
      for (int j = 0; j < 2; ++j) {
        s16x8 b = *(const s16x8*)&Ws[(kt6 * 96 + l * 32 + j * 16 + ar) * 32 + koff];
        acc[l][j][0] = MFMA16(a0, b, acc[l][j][0], 0, 0, 0);
        acc[l][j][1] = MFMA16(a1, b, acc[l][j][1], 0, 0, 0);
      }
  }
  __syncthreads();  // Ws reads done; region becomes P

  // phase-2 prefetch issued early (overlaps P writes + barrier)
  s16x8 zpf0[2], zpf1[2], zpf2[2];
  zpf0[0] = ZLOAD(0, 0); zpf0[1] = ZLOAD(0, 1);
  zpf1[0] = ZLOAD(1, 0); zpf1[1] = ZLOAD(1, 1);
  zpf2[0] = ZLOAD(2, 0); zpf2[1] = ZLOAD(2, 1);

  // acc -> P (packed b32, swizzled slots)
#pragma unroll
  for (int l = 0; l < 3; ++l)
#pragma unroll
    for (int j = 0; j < 2; ++j)
#pragma unroll
      for (int i = 0; i < 2; ++i)
#pragma unroll
        for (int rp = 0; rp < 2; ++rp) {
          const int r = rp * 2;
          const int w = wid * 32 + i * 16 + cr * 4 + r;
          const int o = j * 16 + cc;
          const int lw0 = 0 * 256 + w, lw1 = 256 + w, lw2 = 512 + w;
          (void)lw1; (void)lw2;
          const int lw = l * 256 + w;
          const int addr = o * 768 + ((lw >> 3) ^ (o & 7)) * 8 + (lw & 7);
          unsigned lo16 = (unsigned short)f2bf(acc[l][j][i][r]);
          unsigned hi16 = (unsigned short)f2bf(acc[l][j][i][r + 1]);
          *(unsigned*)&P[addr] = lo16 | (hi16 << 16);
        }
  __syncthreads();  // P visible

  // ---- Phase 2: (own 32 z) x (32 o), K=768 ----
  f32x4 acc2[2][2] = {};
#pragma unroll
  for (int t2 = 0; t2 < 24; ++t2) {
    s16x8 a0, a1;
    if (t2 % 3 == 0)      { a0 = zpf0[0]; a1 = zpf0[1]; }
    else if (t2 % 3 == 1) { a0 = zpf1[0]; a1 = zpf1[1]; }
    else                  { a0 = zpf2[0]; a1 = zpf2[1]; }
    if (t2 < 21) {
      if (t2 % 3 == 0)      { zpf0[0] = ZLOAD(t2 + 3, 0); zpf0[1] = ZLOAD(t2 + 3, 1); }
      else if (t2 % 3 == 1) { zpf1[0] = ZLOAD(t2 + 3, 0); zpf1[1] = ZLOAD(t2 + 3, 1); }
      else                  { zpf2[0] = ZLOAD(t2 + 3, 0); zpf2[1] = ZLOAD(t2 + 3, 1); }
    }
    const int S = t2 * 4 + ks;
    s16x8 b0 = *(const s16x8*)&P[(0 * 16 + ar) * 768 + (S ^ sl) * 8];
    s16x8 b1 = *(const s16x8*)&P[(1 * 16 + ar) * 768 + (S ^ sl) * 8];
    acc2[0][0] = MFMA16(a0, b0, acc2[0][0], 0, 0, 0);
    acc2[0][1] = MFMA16(a0, b1, acc2[0][1], 0, 0, 0);
    acc2[1][0] = MFMA16(a1, b0, acc2[1][0], 0, 0, 0);
    acc2[1][1] = MFMA16(a1, b1, acc2[1][1], 0, 0, 0);
  }
#undef ALOAD
#undef ZLOAD

  // epilogue
  float* og = out + ((size_t)b0 * 256 + bul) * 16384;
#pragma unroll
  for (int i = 0; i < 2; ++i)
#pragma unroll
    for (int j = 0; j < 2; ++j) {
      const float bv = bias[o0 + j * 16 + cc];
#pragma unroll
      for (int r = 0; r < 4; ++r) {
        const int z = wid * 32 + i * 16 + cr * 4 + r;
        og[(size_t)z * 64 + o0 + j * 16 + cc] = fmaxf(acc2[i][j][r] + bv, 0.f);
      }
    }
}

// ---------------------------------------------------------------------------
extern "C" void kernel_launch(void* const* d_in, const int* in_sizes, int n_in,
                              void* d_out, int out_size, void* d_ws, size_t ws_size,
                              hipStream_t stream) {
  const float* H    = (const float*)d_in[0];
  const float* L1   = (const float*)d_in[1];
  const float* L2   = (const float*)d_in[2];
  const float* W    = (const float*)d_in[3];
  const float* bias = (const float*)d_in[4];
  float* out = (float*)d_out;

  char* ws = (char*)d_ws;
  short* L1b   = (short*)ws;                  // 384 KB
  short* L2cat = (short*)(ws + (384 << 10));  // 384 KB
  short* WT    = (short*)(ws + (768 << 10));  // 72 KB
  char* data = ws + (4ull << 20);

  // per-batch: HbT 8 MiB + A2F 24 MiB = 32 MiB
  const size_t perb = 32ull << 20;
  size_t avail = (ws_size > (4ull << 20)) ? ws_size - (4ull << 20) : 0;
  int nb = 1;
  if (avail >= 8 * perb) nb = 8;
  else if (avail >= 4 * perb) nb = 4;
  else if (avail >= 2 * perb) nb = 2;

  short* HbT = (short*)data;
  short* A2F = (short*)(data + (size_t)nb * (8ull << 20));

  k_cvt_l1<<<768, 256, 0, stream>>>(L1, L1b);
  k_build_l2cat<<<dim3(8, 8, 3), dim3(32, 8), 0, stream>>>(L2, L2cat);
  k_build_wt<<<36, 256, 0, stream>>>(W, WT);

  for (int b0 = 0; b0 < 8; b0 += nb) {
    k_cvt_ht<<<dim3(512, 8, nb), dim3(32, 8), 0, stream>>>(H, HbT, b0);
    k_s1<<<dim3(128, 6, nb), 256, 0, stream>>>(L1b, HbT, A2F);
    k_s23<<<nb * 512, 512, 0, stream>>>(A2F, WT, L2cat, bias, out, b0);
  }
}

// Round 8
// 367.955 us; speedup vs baseline: 1.3407x; 1.3407x over previous
//
#include <hip/hip_runtime.h>

typedef __attribute__((ext_vector_type(8))) short s16x8;
typedef __attribute__((ext_vector_type(4))) float f32x4;

#define MFMA16 __builtin_amdgcn_mfma_f32_16x16x32_bf16
#define WAITVM(N) asm volatile("s_waitcnt vmcnt(" #N ")" ::: "memory")
#define SBAR() asm volatile("s_barrier" ::: "memory")
#define WAITLGKM0() asm volatile("s_waitcnt lgkmcnt(0)" ::: "memory")
#define SCHEDB() __builtin_amdgcn_sched_barrier(0)

__device__ __forceinline__ short f2bf(float x) {
  union { float f; unsigned u; } c; c.f = x;
  unsigned r = (c.u + 0x7fffu + ((c.u >> 16) & 1u)) >> 16;
  return (short)r;
}

__device__ __forceinline__ void gld16(const void* g, void* l) {
  __builtin_amdgcn_global_load_lds(
      (const __attribute__((address_space(1))) unsigned*)g,
      (__attribute__((address_space(3))) unsigned*)l, 16, 0, 0);
}

// BK=32 LDS tiles: involution slot ^= (row>>1)&3 on BOTH gld_lds source and
// ds_read (R3-verified, 0 bank conflicts):
//   stage: srow = lane>>2, selem = ((lane&3)^((lane>>3)&3))*8
//   read : koff = ((lane>>4)^((lane>>1)&3))*8
// Race discipline (R8, fixes R7):
//  * block-shared tiles (k_s1): re-stage a buffer ONLY after lgkmcnt(0)+SBAR
//    (all waves' reads complete).
//  * wave-private strips (k_s23): stage-issue pinned after the consuming MFMAs
//    via sched_barrier(0); MFMA issue implies operand ds_reads completed, and
//    in-order issue puts the DMA after them. Never stage into a buffer whose
//    reads haven't been consumed this iteration *before* the sched_barrier.

// ---------------------------------------------------------------------------
// Prep
// ---------------------------------------------------------------------------
__global__ __launch_bounds__(256) void k_cvt_l1(const float* __restrict__ L1,
                                                short* __restrict__ L1b) {
  int i = blockIdx.x * 256 + threadIdx.x;
  L1b[i] = f2bf(L1[i]);
}

__global__ __launch_bounds__(256) void k_build_l2cat(const float* __restrict__ L2,
                                                     short* __restrict__ L2cat) {
  __shared__ float t[32][33];
  const int l = blockIdx.z, w0 = blockIdx.x * 32, z0 = blockIdx.y * 32;
  const int tx = threadIdx.x, ty = threadIdx.y;
  const float* src = L2 + (size_t)l * 65536;
  for (int i = ty; i < 32; i += 8) t[i][tx] = src[(size_t)(w0 + i) * 256 + z0 + tx];
  __syncthreads();
  for (int i = ty; i < 32; i += 8)
    L2cat[(size_t)(z0 + i) * 768 + l * 256 + w0 + tx] = f2bf(t[tx][i]);
}

__global__ __launch_bounds__(256) void k_build_wt(const float* __restrict__ W,
                                                  short* __restrict__ WT) {
  for (int idx = threadIdx.x + blockIdx.x * 256; idx < 192 * 192; idx += 256 * gridDim.x) {
    int lo = idx / 192, kf = idx % 192;
    int l = lo >> 6, o = lo & 63, k = kf / 64, f = kf & 63;
    WT[idx] = f2bf(W[(((size_t)(k * 3 + l) * 64 + f) << 6) + o]);
  }
}

__global__ __launch_bounds__(256) void k_cvt_ht(const float* __restrict__ H,
                                                short* __restrict__ HbT, int b0) {
  __shared__ float t[32][33];
  const int bc = blockIdx.z;
  const int wf0 = blockIdx.x * 32, v0 = blockIdx.y * 32;
  const int tx = threadIdx.x, ty = threadIdx.y;
  const float* src = H + ((size_t)(b0 + bc) * 256 + v0) * 16384;
  for (int i = ty; i < 32; i += 8) t[i][tx] = src[(size_t)i * 16384 + wf0 + tx];
  __syncthreads();
  short* dst = HbT + ((size_t)bc * 16384 + wf0) * 256;
  for (int i = ty; i < 32; i += 8) dst[(size_t)i * 256 + v0 + tx] = f2bf(t[tx][i]);
}

// ---------------------------------------------------------------------------
// S1: A2[((bc*256+u)*256+w)*192 + kk*64+f] = sum_v L1b[kk][u][v]*HbT[bc][w*64+f][v]
// 128x128 tile, BK=32, 2-buffer; per-iter: vmcnt(4); SBAR; reads+MFMA;
// lgkmcnt(0); SBAR; stage t+2 into the just-read buffer.
// ---------------------------------------------------------------------------
__global__ __launch_bounds__(256, 4) void k_s1(const short* __restrict__ L1b,
                                               const short* __restrict__ HbT,
                                               short* __restrict__ A2) {
  __shared__ __align__(16) short At[2][128 * 32];
  __shared__ __align__(16) short Bt[2][128 * 32];
  const int t = threadIdx.x, lane = t & 63, wid = t >> 6;
  const int n0 = blockIdx.x * 128;
  const int kk = blockIdx.y >> 1;
  const int u0 = (blockIdx.y & 1) * 128;
  const int bc = blockIdx.z;
  const short* Ag = L1b + (size_t)kk * 65536;
  const short* Bg = HbT + (size_t)bc * 16384 * 256;
  const int wm = wid >> 1, wn = wid & 1;
  const int srow = lane >> 2;
  const int selem = ((lane & 3) ^ ((lane >> 3) & 3)) * 8;
  const int koff = ((lane >> 4) ^ ((lane >> 1) & 3)) * 8;
  const int ar = lane & 15;
#define S1ISSUE(tt, bi)                                                                 \
  do {                                                                                  \
    const int rb0 = wid * 32, rb1 = wid * 32 + 16;                                      \
    gld16(Ag + (size_t)(u0 + rb0 + srow) * 256 + (tt) * 32 + selem, At[bi] + rb0 * 32); \
    gld16(Ag + (size_t)(u0 + rb1 + srow) * 256 + (tt) * 32 + selem, At[bi] + rb1 * 32); \
    gld16(Bg + (size_t)(n0 + rb0 + srow) * 256 + (tt) * 32 + selem, Bt[bi] + rb0 * 32); \
    gld16(Bg + (size_t)(n0 + rb1 + srow) * 256 + (tt) * 32 + selem, Bt[bi] + rb1 * 32); \
  } while (0)
  S1ISSUE(0, 0);
  S1ISSUE(1, 1);
  f32x4 acc[4][4] = {};
#pragma unroll
  for (int t8 = 0; t8 < 8; ++t8) {
    if (t8 < 7) { WAITVM(4); } else { WAITVM(0); }
    SBAR();  // tile t8 landed in all waves' strips
    const int cur = t8 & 1;
    s16x8 a[4], b[4];
#pragma unroll
    for (int i = 0; i < 4; ++i)
      a[i] = *(const s16x8*)&At[cur][(wm * 64 + i * 16 + ar) * 32 + koff];
#pragma unroll
    for (int j = 0; j < 4; ++j)
      b[j] = *(const s16x8*)&Bt[cur][(wn * 64 + j * 16 + ar) * 32 + koff];
#pragma unroll
    for (int i = 0; i < 4; ++i)
#pragma unroll
      for (int j = 0; j < 4; ++j) acc[i][j] = MFMA16(a[i], b[j], acc[i][j], 0, 0, 0);
    WAITLGKM0();  // this wave's reads of buf[cur] complete
    SBAR();       // all waves' reads complete -> safe to restage buf[cur]
    if (t8 < 6) { S1ISSUE(t8 + 2, cur); }
  }
#undef S1ISSUE
  const int cr = lane >> 4, cc = lane & 15;
#pragma unroll
  for (int i = 0; i < 4; ++i)
#pragma unroll
    for (int j = 0; j < 4; ++j) {
      const int ncol = n0 + wn * 64 + j * 16 + cc;
      const int w = ncol >> 6, f = ncol & 63;
#pragma unroll
      for (int r = 0; r < 4; ++r) {
        const int u = u0 + wm * 64 + i * 16 + cr * 4 + r;
        A2[(((size_t)bc * 256 + u) * 256 + w) * 192 + kk * 64 + f] = f2bf(acc[i][j][r]);
      }
    }
}

// ---------------------------------------------------------------------------
// S2+S3 fused, o-split (2 blocks/bu). LDS 80 KB -> 2 blocks/CU:
//   P/Ws union 48 KB + per-wave 2-deep strips (8 x 2 x 2 KB = 32 KB).
// Wave-private strips: barrier-free K-loops; stage pinned after MFMAs by
// sched_barrier(0). Counted vmcnt(2) steady-state. Phase handoff:
// lgkmcnt(0)+SBAR both sides of the P region reuse.
// ---------------------------------------------------------------------------
__global__ __launch_bounds__(512) void k_s23(const short* __restrict__ A2,
                                             const short* __restrict__ WTg,
                                             const short* __restrict__ L2cat,
                                             const float* __restrict__ bias,
                                             float* __restrict__ out, int b0) {
  __shared__ __align__(16) short P[32 * 768];        // 48 KB; Ws overlays [0,36K)
  __shared__ __align__(16) short AtS[8][2][32 * 32]; // 32 KB
  short* Ws = P;
  const int t = threadIdx.x, lane = t & 63, wid = t >> 6;
  const int bx = blockIdx.x;
  const int bul = (bx & 7) | ((bx >> 4) << 3);  // o-pair 8 apart -> same XCD
  const int o0 = ((bx >> 3) & 1) * 32;
  const int ar = lane & 15, cc = ar, cr = lane >> 4, sl = lane & 7, ks = lane >> 4;
  const int srow = lane >> 2;
  const int selem = ((lane & 3) ^ ((lane >> 3) & 3)) * 8;
  const int koff = ((lane >> 4) ^ ((lane >> 1) & 3)) * 8;
  const short* A2g = A2 + (size_t)bul * 49152;
  short* st0 = &AtS[wid][0][0];
  short* st1 = &AtS[wid][1][0];

#define P1S(tt, st)                                                                      \
  do {                                                                                   \
    gld16(A2g + (size_t)(wid * 32 + srow) * 192 + (tt) * 32 + selem, (st));              \
    gld16(A2g + (size_t)(wid * 32 + 16 + srow) * 192 + (tt) * 32 + selem, (st) + 512);   \
  } while (0)
#define P2S(tt, st)                                                                      \
  do {                                                                                   \
    gld16(L2cat + (size_t)(wid * 32 + srow) * 768 + (tt) * 32 + selem, (st));            \
    gld16(L2cat + (size_t)(wid * 32 + 16 + srow) * 768 + (tt) * 32 + selem, (st) + 512); \
  } while (0)

  // prologue: A2 tiles 0,1 + full Ws stage; full drain (Ws must be resident)
  P1S(0, st0);
  P1S(1, st1);
  for (int s = wid; s < 36; s += 8) {
    const int t6 = s / 6, rb = (s % 6) * 16;
    const int gr = (rb >> 5) * 64 + o0 + (rb & 31);
    gld16(WTg + (size_t)(gr + srow) * 192 + t6 * 32 + selem, Ws + (t6 * 96 + rb) * 32);
  }
  __syncthreads();

  // ---- Phase 1: (96 lo') x (own 32 w), K=192, 6 iters ----
  f32x4 acc[3][2][2] = {};
#pragma unroll
  for (int kt6 = 0; kt6 < 6; ++kt6) {
    if (kt6 >= 2) {
      if (kt6 < 5) { WAITVM(2); } else { WAITVM(0); }
    }
    short* st = (kt6 & 1) ? st1 : st0;
    s16x8 a0 = *(const s16x8*)&st[(0 + ar) * 32 + koff];
    s16x8 a1 = *(const s16x8*)&st[(16 + ar) * 32 + koff];
#pragma unroll
    for (int l = 0; l < 3; ++l)
#pragma unroll
      for (int j = 0; j < 2; ++j) {
        s16x8 b = *(const s16x8*)&Ws[(kt6 * 96 + l * 32 + j * 16 + ar) * 32 + koff];
        acc[l][j][0] = MFMA16(a0, b, acc[l][j][0], 0, 0, 0);
        acc[l][j][1] = MFMA16(a1, b, acc[l][j][1], 0, 0, 0);
      }
    SCHEDB();  // pin stage-issue after the MFMAs (reads consumed)
    if (kt6 < 4) { P1S(kt6 + 2, st); }
  }
  WAITLGKM0();  // this wave's Ws/strip reads complete
  SBAR();       // all waves done reading Ws; region becomes P

  // phase-2 prefetch (strips fully consumed; issue after the barrier)
  P2S(0, st0);
  P2S(1, st1);

  // acc -> P (packed b32, swizzled slots)
#pragma unroll
  for (int l = 0; l < 3; ++l)
#pragma unroll
    for (int j = 0; j < 2; ++j)
#pragma unroll
      for (int i = 0; i < 2; ++i)
#pragma unroll
        for (int rp = 0; rp < 2; ++rp) {
          const int r = rp * 2;
          const int w = wid * 32 + i * 16 + cr * 4 + r;
          const int o = j * 16 + cc;
          const int lw = l * 256 + w;
          const int addr = o * 768 + ((lw >> 3) ^ (o & 7)) * 8 + (lw & 7);
          unsigned lo16 = (unsigned short)f2bf(acc[l][j][i][r]);
          unsigned hi16 = (unsigned short)f2bf(acc[l][j][i][r + 1]);
          *(unsigned*)&P[addr] = lo16 | (hi16 << 16);
        }
  WAITLGKM0();  // P ds_writes drained (gld_lds is vmcnt, unaffected)
  SBAR();       // P visible to all waves

  // ---- Phase 2: (own 32 z) x (32 o), K=768, 24 iters ----
  f32x4 acc2[2][2] = {};
#pragma unroll
  for (int t2 = 0; t2 < 24; ++t2) {
    if (t2 < 23) { WAITVM(2); } else { WAITVM(0); }
    short* st = (t2 & 1) ? st1 : st0;
    s16x8 a0 = *(const s16x8*)&st[(0 + ar) * 32 + koff];
    s16x8 a1 = *(const s16x8*)&st[(16 + ar) * 32 + koff];
    const int S = t2 * 4 + ks;
    s16x8 b0 = *(const s16x8*)&P[(0 * 16 + ar) * 768 + (S ^ sl) * 8];
    s16x8 b1 = *(const s16x8*)&P[(1 * 16 + ar) * 768 + (S ^ sl) * 8];
    acc2[0][0] = MFMA16(a0, b0, acc2[0][0], 0, 0, 0);
    acc2[0][1] = MFMA16(a0, b1, acc2[0][1], 0, 0, 0);
    acc2[1][0] = MFMA16(a1, b0, acc2[1][0], 0, 0, 0);
    acc2[1][1] = MFMA16(a1, b1, acc2[1][1], 0, 0, 0);
    SCHEDB();  // pin stage-issue after the MFMAs
    if (t2 < 22) { P2S(t2 + 2, st); }
  }
#undef P1S
#undef P2S

  // epilogue
  float* og = out + ((size_t)b0 * 256 + bul) * 16384;
#pragma unroll
  for (int i = 0; i < 2; ++i)
#pragma unroll
    for (int j = 0; j < 2; ++j) {
      const float bv = bias[o0 + j * 16 + cc];
#pragma unroll
      for (int r = 0; r < 4; ++r) {
        const int z = wid * 32 + i * 16 + cr * 4 + r;
        og[(size_t)z * 64 + o0 + j * 16 + cc] = fmaxf(acc2[i][j][r] + bv, 0.f);
      }
    }
}

// ---------------------------------------------------------------------------
extern "C" void kernel_launch(void* const* d_in, const int* in_sizes, int n_in,
                              void* d_out, int out_size, void* d_ws, size_t ws_size,
                              hipStream_t stream) {
  const float* H    = (const float*)d_in[0];
  const float* L1   = (const float*)d_in[1];
  const float* L2   = (const float*)d_in[2];
  const float* W    = (const float*)d_in[3];
  const float* bias = (const float*)d_in[4];
  float* out = (float*)d_out;

  char* ws = (char*)d_ws;
  short* L1b   = (short*)ws;                  // 384 KB
  short* L2cat = (short*)(ws + (384 << 10));  // 384 KB
  short* WT    = (short*)(ws + (768 << 10));  // 72 KB
  char* data = ws + (4ull << 20);

  // per-batch: HbT 8 MiB + A2 24 MiB = 32 MiB
  const size_t perb = 32ull << 20;
  size_t avail = (ws_size > (4ull << 20)) ? ws_size - (4ull << 20) : 0;
  int nb = 1;
  if (avail >= 8 * perb) nb = 8;
  else if (avail >= 4 * perb) nb = 4;
  else if (avail >= 2 * perb) nb = 2;

  short* HbT = (short*)data;
  short* A2  = (short*)(data + (size_t)nb * (8ull << 20));

  k_cvt_l1<<<768, 256, 0, stream>>>(L1, L1b);
  k_build_l2cat<<<dim3(8, 8, 3), dim3(32, 8), 0, stream>>>(L2, L2cat);
  k_build_wt<<<36, 256, 0, stream>>>(W, WT);

  for (int b0 = 0; b0 < 8; b0 += nb) {
    k_cvt_ht<<<dim3(512, 8, nb), dim3(32, 8), 0, stream>>>(H, HbT, b0);
    k_s1<<<dim3(128, 6, nb), 256, 0, stream>>>(L1b, HbT, A2);
    k_s23<<<nb * 512, 512, 0, stream>>>(A2, WT, L2cat, bias, out, b0);
  }
}

// Round 9
// 323.646 us; speedup vs baseline: 1.5242x; 1.1369x over previous
//
#include <hip/hip_runtime.h>

typedef __attribute__((ext_vector_type(8))) short s16x8;
typedef __attribute__((ext_vector_type(4))) float f32x4;

#define MFMA16 __builtin_amdgcn_mfma_f32_16x16x32_bf16
#define WAITVM(N) asm volatile("s_waitcnt vmcnt(" #N ")" ::: "memory")
#define SBAR() asm volatile("s_barrier" ::: "memory")
#define WAITLGKM0() asm volatile("s_waitcnt lgkmcnt(0)" ::: "memory")
#define SCHEDB() __builtin_amdgcn_sched_barrier(0)

__device__ __forceinline__ short f2bf(float x) {
  union { float f; unsigned u; } c; c.f = x;
  unsigned r = (c.u + 0x7fffu + ((c.u >> 16) & 1u)) >> 16;
  return (short)r;
}

__device__ __forceinline__ void gld16(const void* g, void* l) {
  __builtin_amdgcn_global_load_lds(
      (const __attribute__((address_space(1))) unsigned*)g,
      (__attribute__((address_space(3))) unsigned*)l, 16, 0, 0);
}

// BK=32 LDS tiles: involution slot ^= (row>>1)&3 on BOTH gld_lds source and
// ds_read (R3-verified, 0 bank conflicts):
//   stage: srow = lane>>2, selem = ((lane&3)^((lane>>3)&3))*8
//   read : koff = ((lane>>4)^((lane>>1)&3))*8
// Race discipline (R8-proven): wave-private strips restage the just-consumed
// buffer only AFTER the MFMAs, pinned by sched_barrier(0). Cross-wave LDS
// handoffs use lgkmcnt(0)+s_barrier on both sides.

// ---------------------------------------------------------------------------
// Prep
// ---------------------------------------------------------------------------
__global__ __launch_bounds__(256) void k_cvt_l1(const float* __restrict__ L1,
                                                short* __restrict__ L1b) {
  int i = blockIdx.x * 256 + threadIdx.x;
  L1b[i] = f2bf(L1[i]);
}

__global__ __launch_bounds__(256) void k_build_l2cat(const float* __restrict__ L2,
                                                     short* __restrict__ L2cat) {
  __shared__ float t[32][33];
  const int l = blockIdx.z, w0 = blockIdx.x * 32, z0 = blockIdx.y * 32;
  const int tx = threadIdx.x, ty = threadIdx.y;
  const float* src = L2 + (size_t)l * 65536;
  for (int i = ty; i < 32; i += 8) t[i][tx] = src[(size_t)(w0 + i) * 256 + z0 + tx];
  __syncthreads();
  for (int i = ty; i < 32; i += 8)
    L2cat[(size_t)(z0 + i) * 768 + l * 256 + w0 + tx] = f2bf(t[tx][i]);
}

__global__ __launch_bounds__(256) void k_build_wt(const float* __restrict__ W,
                                                  short* __restrict__ WT) {
  for (int idx = threadIdx.x + blockIdx.x * 256; idx < 192 * 192; idx += 256 * gridDim.x) {
    int lo = idx / 192, kf = idx % 192;
    int l = lo >> 6, o = lo & 63, k = kf / 64, f = kf & 63;
    WT[idx] = f2bf(W[(((size_t)(k * 3 + l) * 64 + f) << 6) + o]);
  }
}

__global__ __launch_bounds__(256) void k_cvt_ht(const float* __restrict__ H,
                                                short* __restrict__ HbT, int b0) {
  __shared__ float t[32][33];
  const int bc = blockIdx.z;
  const int wf0 = blockIdx.x * 32, v0 = blockIdx.y * 32;
  const int tx = threadIdx.x, ty = threadIdx.y;
  const float* src = H + ((size_t)(b0 + bc) * 256 + v0) * 16384;
  for (int i = ty; i < 32; i += 8) t[i][tx] = src[(size_t)i * 16384 + wf0 + tx];
  __syncthreads();
  short* dst = HbT + ((size_t)bc * 16384 + wf0) * 256;
  for (int i = ty; i < 32; i += 8) dst[(size_t)i * 256 + v0 + tx] = f2bf(t[tx][i]);
}

// ---------------------------------------------------------------------------
// S1 (R5 form — fastest measured): A2[((bc*256+u)*256+w)*192 + kk*64+f]
//   = sum_v L1b[kk][u][v]*HbT[bc][w*64+f][v]
// 128x128 tile, BK=32, double-buffered, stage-before-MFMA, syncthreads.
// ---------------------------------------------------------------------------
__global__ __launch_bounds__(256, 4) void k_s1(const short* __restrict__ L1b,
                                               const short* __restrict__ HbT,
                                               short* __restrict__ A2) {
  __shared__ __align__(16) short At[2][128 * 32];
  __shared__ __align__(16) short Bt[2][128 * 32];
  const int t = threadIdx.x, lane = t & 63, wid = t >> 6;
  const int n0 = blockIdx.x * 128;
  const int kk = blockIdx.y >> 1;
  const int u0 = (blockIdx.y & 1) * 128;
  const int bc = blockIdx.z;
  const short* Ag = L1b + (size_t)kk * 65536;
  const short* Bg = HbT + (size_t)bc * 16384 * 256;
  const int wm = wid >> 1, wn = wid & 1;
  const int srow = lane >> 2;
  const int selem = ((lane & 3) ^ ((lane >> 3) & 3)) * 8;
  const int koff = ((lane >> 4) ^ ((lane >> 1) & 3)) * 8;
  const int ar = lane & 15;
#pragma unroll
  for (int j = 0; j < 2; ++j) {
    const int rb = wid * 32 + j * 16;
    gld16(Ag + (size_t)(u0 + rb + srow) * 256 + selem, At[0] + rb * 32);
    gld16(Bg + (size_t)(n0 + rb + srow) * 256 + selem, Bt[0] + rb * 32);
  }
  __syncthreads();
  f32x4 acc[4][4] = {};
#pragma unroll
  for (int kt8 = 0; kt8 < 8; ++kt8) {
    const int cur = kt8 & 1;
    s16x8 a[4], b[4];
#pragma unroll
    for (int i = 0; i < 4; ++i)
      a[i] = *(const s16x8*)&At[cur][(wm * 64 + i * 16 + ar) * 32 + koff];
#pragma unroll
    for (int j = 0; j < 4; ++j)
      b[j] = *(const s16x8*)&Bt[cur][(wn * 64 + j * 16 + ar) * 32 + koff];
    if (kt8 < 7) {
#pragma unroll
      for (int j = 0; j < 2; ++j) {
        const int rb = wid * 32 + j * 16;
        gld16(Ag + (size_t)(u0 + rb + srow) * 256 + (kt8 + 1) * 32 + selem, At[cur ^ 1] + rb * 32);
        gld16(Bg + (size_t)(n0 + rb + srow) * 256 + (kt8 + 1) * 32 + selem, Bt[cur ^ 1] + rb * 32);
      }
    }
#pragma unroll
    for (int i = 0; i < 4; ++i)
#pragma unroll
      for (int j = 0; j < 4; ++j) acc[i][j] = MFMA16(a[i], b[j], acc[i][j], 0, 0, 0);
    __syncthreads();
  }
  const int cr = lane >> 4, cc = lane & 15;
#pragma unroll
  for (int i = 0; i < 4; ++i)
#pragma unroll
    for (int j = 0; j < 4; ++j) {
      const int ncol = n0 + wn * 64 + j * 16 + cc;
      const int w = ncol >> 6, f = ncol & 63;
#pragma unroll
      for (int r = 0; r < 4; ++r) {
        const int u = u0 + wm * 64 + i * 16 + cr * 4 + r;
        A2[(((size_t)bc * 256 + u) * 256 + w) * 192 + kk * 64 + f] = f2bf(acc[i][j][r]);
      }
    }
}

// ---------------------------------------------------------------------------
// S2+S3 fused, ONE block per bu (512 thr, full 64-o): halves L2cat/A2 L2
// traffic vs o-split. LDS 144 KB (1 block/CU): P[64][768] 96K (Ws 72K
// overlaid) + depth-3 wave-private strips 8x3x2K = 48K.
// Phase 1: (192 lo) x (own 32 w), K=192: a=A2 strips, b=Ws, 24 MFMA/iter.
// Phase 2: (own 32 z) x (64 o), K=768: a=L2cat strips, b=P, 8 MFMA/iter.
// Counted vmcnt: steady VM(4), tail VM(2)/VM(0); depth-3 lookahead.
// ---------------------------------------------------------------------------
__global__ __launch_bounds__(512, 2) void k_s23(const short* __restrict__ A2,
                                                const short* __restrict__ WTg,
                                                const short* __restrict__ L2cat,
                                                const float* __restrict__ bias,
                                                float* __restrict__ out, int b0) {
  __shared__ __align__(16) short P[64 * 768];        // 96 KB; Ws overlays [0,72K)
  __shared__ __align__(16) short AtS[8][3][32 * 32]; // 48 KB strips
  short* Ws = P;
  const int t = threadIdx.x, lane = t & 63, wid = t >> 6;
  const int bul = blockIdx.x;
  const int ar = lane & 15, cc = ar, cr = lane >> 4, sl = lane & 7, ks = lane >> 4;
  const int srow = lane >> 2;
  const int selem = ((lane & 3) ^ ((lane >> 3) & 3)) * 8;
  const int koff = ((lane >> 4) ^ ((lane >> 1) & 3)) * 8;
  const short* A2g = A2 + (size_t)bul * 49152;

#define P1S(tt, bi)                                                                        \
  do {                                                                                     \
    gld16(A2g + (size_t)(wid * 32 + srow) * 192 + (tt) * 32 + selem, &AtS[wid][bi][0]);    \
    gld16(A2g + (size_t)(wid * 32 + 16 + srow) * 192 + (tt) * 32 + selem,                  \
          &AtS[wid][bi][512]);                                                             \
  } while (0)
#define P2S(tt, bi)                                                                        \
  do {                                                                                     \
    gld16(L2cat + (size_t)(wid * 32 + srow) * 768 + (tt) * 32 + selem, &AtS[wid][bi][0]);  \
    gld16(L2cat + (size_t)(wid * 32 + 16 + srow) * 768 + (tt) * 32 + selem,                \
          &AtS[wid][bi][512]);                                                             \
  } while (0)

  // prologue: A2 tiles 0-2 + full Ws (192 lo x 192 kf, 72 gld16 groups)
  P1S(0, 0);
  P1S(1, 1);
  P1S(2, 2);
  for (int s = wid; s < 72; s += 8) {
    const int t6 = s / 12, g = (s % 12) * 16;
    gld16(WTg + (size_t)(g + srow) * 192 + t6 * 32 + selem, Ws + ((size_t)t6 * 192 + g) * 32);
  }
  __syncthreads();  // full drain: tiles 0-2 + Ws resident; vmcnt = 0

  // ---- Phase 1: (192 lo) x (own 32 w), K=192, 6 iters ----
  f32x4 acc[12][2] = {};
#pragma unroll
  for (int kt6 = 0; kt6 < 6; ++kt6) {
    if (kt6 == 3) { WAITVM(4); } else if (kt6 == 4) { WAITVM(2); } else if (kt6 == 5) { WAITVM(0); }
    const short* stc = &AtS[wid][kt6 % 3][0];
    s16x8 a0 = *(const s16x8*)&stc[(0 + ar) * 32 + koff];
    s16x8 a1 = *(const s16x8*)&stc[(16 + ar) * 32 + koff];
#pragma unroll
    for (int j2 = 0; j2 < 12; ++j2) {
      s16x8 b = *(const s16x8*)&Ws[((size_t)kt6 * 192 + j2 * 16 + ar) * 32 + koff];
      acc[j2][0] = MFMA16(a0, b, acc[j2][0], 0, 0, 0);
      acc[j2][1] = MFMA16(a1, b, acc[j2][1], 0, 0, 0);
    }
    SCHEDB();  // pin restage after the MFMAs (this iter's strip reads consumed)
    if (kt6 == 0) { P1S(3, 0); } else if (kt6 == 1) { P1S(4, 1); } else if (kt6 == 2) { P1S(5, 2); }
  }
  WAITLGKM0();  // this wave's Ws/strip reads complete
  SBAR();       // all waves done reading Ws; region becomes P

  // phase-2 prefetch into strips (strips fully consumed in phase 1)
  P2S(0, 0);
  P2S(1, 1);
  P2S(2, 2);

  // acc -> P (packed b32, swizzled slots)
#pragma unroll
  for (int j2 = 0; j2 < 12; ++j2)
#pragma unroll
    for (int i = 0; i < 2; ++i)
#pragma unroll
      for (int rp = 0; rp < 2; ++rp) {
        const int r = rp * 2;
        const int w = wid * 32 + i * 16 + cr * 4 + r;
        const int lo = j2 * 16 + cc;
        const int l = lo >> 6, o = lo & 63;
        const int lw = l * 256 + w;
        const int addr = o * 768 + ((lw >> 3) ^ (o & 7)) * 8 + (lw & 7);
        unsigned lo16 = (unsigned short)f2bf(acc[j2][i][r]);
        unsigned hi16 = (unsigned short)f2bf(acc[j2][i][r + 1]);
        *(unsigned*)&P[addr] = lo16 | (hi16 << 16);
      }
  WAITLGKM0();  // P ds_writes drained (gld_lds is vmcnt, unaffected)
  SBAR();       // P visible to all waves

  // ---- Phase 2: (own 32 z) x (64 o), K=768, 24 iters ----
  f32x4 acc2[2][4] = {};
#pragma unroll
  for (int t2 = 0; t2 < 24; ++t2) {
    if (t2 < 22) { WAITVM(4); } else if (t2 == 22) { WAITVM(2); } else { WAITVM(0); }
    const short* stc = &AtS[wid][t2 % 3][0];
    s16x8 a0 = *(const s16x8*)&stc[(0 + ar) * 32 + koff];
    s16x8 a1 = *(const s16x8*)&stc[(16 + ar) * 32 + koff];
    const int S = t2 * 4 + ks;
#pragma unroll
    for (int j = 0; j < 4; ++j) {
      s16x8 b = *(const s16x8*)&P[(j * 16 + ar) * 768 + (S ^ sl) * 8];
      acc2[0][j] = MFMA16(a0, b, acc2[0][j], 0, 0, 0);
      acc2[1][j] = MFMA16(a1, b, acc2[1][j], 0, 0, 0);
    }
    SCHEDB();  // pin restage after the MFMAs
    if (t2 < 21) {
      if (t2 % 3 == 0) { P2S(t2 + 3, 0); } else if (t2 % 3 == 1) { P2S(t2 + 3, 1); } else { P2S(t2 + 3, 2); }
    }
  }
#undef P1S
#undef P2S

  // epilogue
  float* og = out + ((size_t)b0 * 256 + bul) * 16384;
#pragma unroll
  for (int i = 0; i < 2; ++i)
#pragma unroll
    for (int j = 0; j < 4; ++j) {
      const float bv = bias[j * 16 + cc];
#pragma unroll
      for (int r = 0; r < 4; ++r) {
        const int z = wid * 32 + i * 16 + cr * 4 + r;
        og[(size_t)z * 64 + j * 16 + cc] = fmaxf(acc2[i][j][r] + bv, 0.f);
      }
    }
}

// ---------------------------------------------------------------------------
extern "C" void kernel_launch(void* const* d_in, const int* in_sizes, int n_in,
                              void* d_out, int out_size, void* d_ws, size_t ws_size,
                              hipStream_t stream) {
  const float* H    = (const float*)d_in[0];
  const float* L1   = (const float*)d_in[1];
  const float* L2   = (const float*)d_in[2];
  const float* W    = (const float*)d_in[3];
  const float* bias = (const float*)d_in[4];
  float* out = (float*)d_out;

  char* ws = (char*)d_ws;
  short* L1b   = (short*)ws;                  // 384 KB
  short* L2cat = (short*)(ws + (384 << 10));  // 384 KB
  short* WT    = (short*)(ws + (768 << 10));  // 72 KB
  char* data = ws + (4ull << 20);

  // per-batch: HbT 8 MiB + A2 24 MiB = 32 MiB
  const size_t perb = 32ull << 20;
  size_t avail = (ws_size > (4ull << 20)) ? ws_size - (4ull << 20) : 0;
  int nb = 1;
  if (avail >= 8 * perb) nb = 8;
  else if (avail >= 4 * perb) nb = 4;
  else if (avail >= 2 * perb) nb = 2;

  short* HbT = (short*)data;
  short* A2  = (short*)(data + (size_t)nb * (8ull << 20));

  k_cvt_l1<<<768, 256, 0, stream>>>(L1, L1b);
  k_build_l2cat<<<dim3(8, 8, 3), dim3(32, 8), 0, stream>>>(L2, L2cat);
  k_build_wt<<<36, 256, 0, stream>>>(W, WT);

  for (int b0 = 0; b0 < 8; b0 += nb) {
    k_cvt_ht<<<dim3(512, 8, nb), dim3(32, 8), 0, stream>>>(H, HbT, b0);
    k_s1<<<dim3(128, 6, nb), 256, 0, stream>>>(L1b, HbT, A2);
    k_s23<<<nb * 256, 512, 0, stream>>>(A2, WT, L2cat, bias, out, b0);
  }
}